// Round 1
// baseline (70.912 us; speedup 1.0000x reference)
//
#include <hip/hip_runtime.h>
#include <math.h>

// d_in order: X[300000,256] f32, y[300000,1] f32, Z[1000,8] f32,
//             beta_w[1,256] f32, gamma_w[1,8] f32, theta[1] f32
// ws layout (floats): [0..3] = {s1, s2, v, r}; [16..16+nblocks) = block partials

__global__ __launch_bounds__(256) void k_scalars(const float* __restrict__ Z,
                                                 const float* __restrict__ gamma_w,
                                                 const float* __restrict__ theta,
                                                 float* __restrict__ ws,
                                                 int n_study) {
    __shared__ double red1[256];
    __shared__ double red2[256];
    int t = threadIdx.x;
    float g[8];
#pragma unroll
    for (int j = 0; j < 8; ++j) g[j] = gamma_w[j];
    double s1 = 0.0, s2 = 0.0;
    for (int s = t; s < n_study; s += 256) {
        float d = 0.f;
#pragma unroll
        for (int j = 0; j < 8; ++j) d = fmaf(Z[s * 8 + j], g[j], d);
        double mu = exp((double)d);
        s1 += mu;
        s2 += mu * mu;
    }
    red1[t] = s1;
    red2[t] = s2;
    __syncthreads();
    for (int off = 128; off; off >>= 1) {
        if (t < off) {
            red1[t] += red1[t + off];
            red2[t] += red2[t + off];
        }
        __syncthreads();
    }
    if (t == 0) {
        double S1 = red1[0], S2 = red2[0];
        double th = (double)theta[0];
        double sig = 1.0 / (1.0 + exp(-th));
        double alpha = 100.0 * (double)n_study * sig + 1e-8;
        double est = alpha * S2 / (S1 * S1);   // == mean(voxel_sum_alpha), voxel-independent
        double v = 1.0 / est;
        double r = v * S1 * S1 / S2;
        ws[0] = (float)S1;
        ws[1] = (float)S2;
        ws[2] = (float)v;
        ws[3] = (float)r;
    }
}

__global__ __launch_bounds__(256) void k_main(const float4* __restrict__ X4,
                                              const float* __restrict__ y,
                                              const float4* __restrict__ beta4,
                                              const float* __restrict__ consts,
                                              float* __restrict__ partials,
                                              int V) {
    const int lane = threadIdx.x & 63;
    const int wib  = threadIdx.x >> 6;          // wave in block (0..3)
    const int wave = blockIdx.x * 4 + wib;

    const float4 b = beta4[lane];               // beta fragment: cols 4*lane..4*lane+3
    const float s1 = consts[0];
    const float s2 = consts[1];
    const float v  = consts[2];
    const float r  = consts[3];

    const int row0 = wave << 6;
    float term = 0.f;

    if (row0 < V) {
        const int nrows = min(64, V - row0);
        float dmine = 0.f;
        const float4* Xrow = X4 + (size_t)row0 * 64;
        for (int rr = 0; rr < nrows; ++rr) {
            float4 xv = Xrow[(size_t)rr * 64 + lane];
            float d = fmaf(xv.x, b.x, fmaf(xv.y, b.y, fmaf(xv.z, b.z, xv.w * b.w)));
#pragma unroll
            for (int m = 32; m; m >>= 1) d += __shfl_xor(d, m, 64);
            if (lane == rr) dmine = d;          // lane rr owns row rr's dot
        }
        if (lane < nrows) {
            const float yv = y[row0 + lane];
            const float mu = expf(dmine);
            const float num = mu * mu * s2;               // numerator
            const float p = num / fmaf(v * s1, mu, num);  // num / (v*mu*s1 + num)
            float t = r * log1pf(-p) + yv * logf(p);
            const int yi = (int)yv;
            for (int k = 0; k < yi; ++k)                  // lgamma(y+r)-lgamma(r)-lgamma(y+1)
                t += logf((r + (float)k) / (float)(k + 1));
            term = t;
        }
    }

    // wave reduce, then block reduce across 4 waves
#pragma unroll
    for (int m = 32; m; m >>= 1) term += __shfl_xor(term, m, 64);
    __shared__ float bl[4];
    if (lane == 0) bl[wib] = term;
    __syncthreads();
    if (threadIdx.x == 0) partials[blockIdx.x] = bl[0] + bl[1] + bl[2] + bl[3];
}

__global__ __launch_bounds__(256) void k_reduce(const float* __restrict__ partials,
                                                int n, float* __restrict__ out) {
    __shared__ double red[256];
    int t = threadIdx.x;
    double s = 0.0;
    for (int i = t; i < n; i += 256) s += (double)partials[i];
    red[t] = s;
    __syncthreads();
    for (int off = 128; off; off >>= 1) {
        if (t < off) red[t] += red[t + off];
        __syncthreads();
    }
    if (t == 0) out[0] = (float)(-red[0]);
}

extern "C" void kernel_launch(void* const* d_in, const int* in_sizes, int n_in,
                              void* d_out, int out_size, void* d_ws, size_t ws_size,
                              hipStream_t stream) {
    const float* X       = (const float*)d_in[0];
    const float* y       = (const float*)d_in[1];
    const float* Z       = (const float*)d_in[2];
    const float* beta_w  = (const float*)d_in[3];
    const float* gamma_w = (const float*)d_in[4];
    const float* theta   = (const float*)d_in[5];

    const int V       = in_sizes[0] / 256;
    const int n_study = in_sizes[2] / 8;

    float* ws       = (float*)d_ws;
    float* consts   = ws;
    float* partials = ws + 16;

    const int nwaves  = (V + 63) / 64;
    const int nblocks = (nwaves + 3) / 4;

    k_scalars<<<1, 256, 0, stream>>>(Z, gamma_w, theta, ws, n_study);
    k_main<<<nblocks, 256, 0, stream>>>((const float4*)X, y, (const float4*)beta_w,
                                        consts, partials, V);
    k_reduce<<<1, 256, 0, stream>>>(partials, nblocks, (float*)d_out);
}